// Round 4
// baseline (238.995 us; speedup 1.0000x reference)
//
#include <hip/hip_runtime.h>

// CRF NLL: B=1024, S=512, T=48.
// R8: R7 skeleton (block = 2 waves: wave0 fwd alpha chain, wave1 bwd beta
// chain; SGPR state broadcast via v_readlane; chains meet at nf) with the
// emission prefetch ring deepened 4 -> 16.
// Diagnosis: R4/R6/R7 all show a fixed ~700-900 cyc/step stall independent
// of VALU work, TLP, and LDS presence.  Common factor: each step consumes
// a cold-HBM emission load issued only 4 steps earlier -> s_waitcnt vmcnt
// floor = lat/4 with effective latency 2-4k cyc under 2048-wave load.
// Ring depth 16 (fully unrolled 16-step blocks, named registers, uniform
// 'live' predication for the tail) drops the floor to lat/16, below the
// compute critical path.  Also: pair-exchange in the broadcast now uses
// DPP quad_perm(1,0,3,2) instead of __shfl_xor (ds_swizzle) -- removes the
// last DS op from the serial chain.
// Per-step math byte-identical to R7: E' = exp(trans)*2^-8 in f16,
// dest-weight on fwd / publish-weight on bwd, exact pow2 probe-rescale at
// global steps == 3 mod 4, 60000 clamp on published f16 values.

#define T 48
#define SLEN 512
#define BATCH 1024

typedef _Float16 h2 __attribute__((ext_vector_type(2)));

__device__ __forceinline__ float wave_sum(float v) {
#pragma unroll
    for (int m = 32; m >= 1; m >>= 1) v += __shfl_xor(v, m, 64);
    return v;
}
__device__ __forceinline__ float wave_max(float v) {
#pragma unroll
    for (int m = 32; m >= 1; m >>= 1) v = fmaxf(v, __shfl_xor(v, m, 64));
    return v;
}
__device__ __forceinline__ float rlane(float v, int k) {
    return __int_as_float(__builtin_amdgcn_readlane(__float_as_int(v), k));
}
__device__ __forceinline__ float fdot2(h2 a, h2 b, float c) {
#if __has_builtin(__builtin_amdgcn_fdot2)
    return __builtin_amdgcn_fdot2(a, b, c, false);
#else
    return fmaf((float)a[1], (float)b[1], fmaf((float)a[0], (float)b[0], c));
#endif
}

// state pair k as h2 from the SGPR array
#define QH(S, k) (__builtin_bit_cast(h2, (S)[k]))

// 48-long dot: 24 fdot2 into 4 accumulator chains (depth 6 each)
#define DOTS48(S, E, A0, A1, A2, A3)                 \
    _Pragma("unroll")                                \
    for (int t = 0; t < 24; t += 4) {                \
        A0 = fdot2(QH(S, t + 0), E[t + 0], A0);      \
        A1 = fdot2(QH(S, t + 1), E[t + 1], A1);      \
        A2 = fdot2(QH(S, t + 2), E[t + 2], A2);      \
        A3 = fdot2(QH(S, t + 3), E[t + 3], A3);      \
    }

// publish: lane j holds state value VAL (f32, already clamped/scaled);
// cvt to f16 (RTE), exchange with xor-1 neighbor via DPP quad_perm
// (pure VALU, no LDS), pack (even,odd), readlane even lanes 0..46 into
// DST[0..23] (wave-uniform -> SGPRs).
#define BCAST24(DST, VAL)                                                 \
    {                                                                     \
        unsigned hp_ = (unsigned)__builtin_bit_cast(unsigned short,       \
                          (_Float16)(VAL));                               \
        unsigned op_ = (unsigned)__builtin_amdgcn_update_dpp(             \
                          (int)hp_, (int)hp_, 0xB1, 0xF, 0xF, false);     \
        unsigned pk_ = (lane & 1) ? (op_ | (hp_ << 16))                   \
                                  : (hp_ | (op_ << 16));                  \
        _Pragma("unroll")                                                 \
        for (int k = 0; k < 24; ++k)                                      \
            (DST)[k] = (unsigned)__builtin_amdgcn_readlane((int)pk_,      \
                                                            2 * k);       \
    }

__global__ __launch_bounds__(128) void crf_kernel(
    const float* __restrict__ em,      // (B,S,T)
    const int*   __restrict__ tags,    // (B,S)
    const float* __restrict__ mask,    // (B,S)
    const float* __restrict__ trans,   // (T,T)
    const float* __restrict__ start_t, // (T,)
    const float* __restrict__ end_t,   // (T,)
    float*       __restrict__ out)     // scalar
{
    constexpr float LOG2E = 1.4426950408889634f;
    constexpr float LN2   = 0.6931471805599453f;
    constexpr float ESC   = -8.0f;     // fold 2^-8 into E' for f16 range

    const int b    = blockIdx.x;
    const int tid  = threadIdx.x;
    const int w    = tid >> 6;         // 0 = forward chain, 1 = backward
    const int lane = tid & 63;
    const int j    = lane < T ? lane : (T - 1);

    const float* em_b   = em   + (size_t)b * SLEN * T;
    const float* mask_b = mask + (size_t)b * SLEN;
    const int*   tags_b = tags + (size_t)b * SLEN;

    // ---- sequence length (each wave for itself; force scalar) ----
    float msum = 0.f;
    for (int s = lane; s < SLEN; s += 64) msum += mask_b[s];
    msum = wave_sum(msum);
    const int len = __builtin_amdgcn_readfirstlane((int)(msum + 0.5f));
    const int nb  = (len - 1) >> 1;           // bwd steps
    const int nf  = (len - 1) - nb;           // fwd steps = nb or nb+1
    const int steps = w ? nb : nf;

    // ---- packed E' fragments: wave0 col j, wave1 row j, pairs over k ----
    h2 E[24];
#pragma unroll
    for (int k = 0; k < T; k += 2) {
        const int i0 = w ? (j * T + k)     : (k * T + j);
        const int i1 = w ? (j * T + k + 1) : ((k + 1) * T + j);
        h2 e;
        e[0] = (_Float16)exp2f(trans[i0] * LOG2E + ESC);
        e[1] = (_Float16)exp2f(trans[i1] * LOG2E + ESC);
        E[k >> 1] = e;
    }

    const float* ep = em_b + j;
    const int maxoff = (SLEN - 1) * T;

    // ---- init state + initial broadcast ----
    float st, L, pubinit;
    if (w == 0) {
        const float z0 = (start_t[j] + em_b[j]) * LOG2E;
        const float m0 = wave_max(z0);
        st = exp2f(z0 - m0); L = m0;
        pubinit = st;
    } else {
        st = exp2f(end_t[j] * LOG2E); L = 0.f;
        const float vlast = ep[(size_t)(len - 1) * T];
        pubinit = fminf(st * exp2f(vlast * LOG2E), 60000.f);
    }
    unsigned sf[24];
    BCAST24(sf, pubinit)

    // ---- gold path score (forward wave only) ----
    float g = 0.f;
    if (w == 0) {
        for (int i = lane; i < len; i += 64) {
            if (i >= 1) {
                const int tc = tags_b[i];
                const int tp = tags_b[i - 1];
                g += trans[tc * T + tp] + em_b[(size_t)i * T + tc];
            }
        }
        g = wave_sum(g);
    }

    // ---- emission ring, 16 deep (use-distance = 16 steps) ----
    const int dlt = w ? -T : T;
    int off = w ? (len - 2) * T : T;
    auto ldem = [&]() -> float {
        int oc = off;
        oc = oc < 0 ? 0 : oc;
        oc = oc > maxoff ? maxoff : oc;
        const float r = ep[oc];
        off += dlt;
        return r;
    };
    float fr[16];
#pragma unroll
    for (int k = 0; k < 16; ++k) fr[k] = ldem();

    auto rescale = [&](float& v) {   // exact pow2, 4-lane probe
        float m = fmaxf(fmaxf(rlane(v, 0), rlane(v, 16)),
                        fmaxf(rlane(v, 32), rlane(v, 47)));
        int e = ((__float_as_int(m) >> 23) & 255) - 127;
        e = e < -64 ? -64 : e;
        v *= __int_as_float((127 - e) << 23);
        L += (float)e;
    };

    auto step = [&](float& fe, bool live, bool resc) {
        const float wv = exp2f(fe * LOG2E);
        fe = ldem();                        // refill slot, used 16 steps later
        float a0 = 0.f, a1 = 0.f, a2 = 0.f, a3 = 0.f;
        DOTS48(sf, E, a0, a1, a2, a3)
        float s = (a0 + a1) + (a2 + a3);
        if (w == 0) s *= wv;                // fwd: dest-weight at compute
        if (live) {                         // uniform predicate (tail block)
            if (resc) rescale(s);
            st = s;
            const float pub = fminf(w ? s * wv : s, 60000.f);  // bwd: weight at publish
            BCAST24(sf, pub)
        }
    };

    for (int base = 0; base < steps; base += 16) {
#pragma unroll
        for (int k = 0; k < 16; ++k)
            step(fr[k], (base + k) < steps, ((k & 3) == 3));
    }

    // ---- combine in-block: Z = sum_j p_nf[j] * beta_nf[j] ----
    __shared__ float shu[T];
    __shared__ float shL[2];
    if (w == 0) {
        if (lane == 0) shL[0] = L + 8.0f * (float)nf;  // undo folded 2^-8
    } else {
        if (lane < T) shu[lane] = st;
        if (lane == 0) shL[1] = L + 8.0f * (float)nb;
    }
    __syncthreads();
    if (w == 0) {
        const float v  = (lane < T) ? st * shu[lane] : 0.f;
        const float S_ = wave_sum(v);
        const float fwd = (shL[0] + shL[1] + log2f(S_)) * LN2;
        if (lane == 0) {
            const int t0 = tags_b[0];
            const int tl = tags_b[len - 1];
            const float gold = g + start_t[t0] + em_b[t0] + end_t[tl];
            atomicAdd(out, (fwd - gold) * (1.0f / (float)BATCH));
        }
    }
}

extern "C" void kernel_launch(void* const* d_in, const int* in_sizes, int n_in,
                              void* d_out, int out_size, void* d_ws, size_t ws_size,
                              hipStream_t stream) {
    const float* em      = (const float*)d_in[0];
    const int*   tags    = (const int*)  d_in[1];
    const float* mask    = (const float*)d_in[2];
    const float* trans   = (const float*)d_in[3];
    const float* start_t = (const float*)d_in[4];
    const float* end_t   = (const float*)d_in[5];
    float* out = (float*)d_out;

    hipMemsetAsync(out, 0, sizeof(float), stream);
    crf_kernel<<<BATCH, 128, 0, stream>>>(em, tags, mask, trans, start_t, end_t, out);
}